// Round 1
// baseline (468.163 us; speedup 1.0000x reference)
//
#include <hip/hip_runtime.h>

// HierarchicalGraphConv — exploits the reference's v[tgt] identity:
// softmax weights sum to 1 per target/head, so agg[n] = v[n] (if n has an
// incoming edge) else 0. Full level = LN(nodes + mask*(nodes@Wv@Wo + bv@Wo) + bo-term).

#define N0 40000
#define N1 10000
#define N2 2000
#define N3 400
#define NTOT 52400
#define E0 320000
#define E1 160000
#define E2 32000
#define E3 6400

// ws layout:
//   flags (u8)  @ 0        : 52400 B
//   WcT (f32)   @ 65536    : 4*128*128 = 262144 B   (WcT[l][j][k] = (Wv@Wo)[k][j])
//   cc  (f32)   @ 327680   : 4*128 floats           (bv@Wo + bo)
#define WS_WCT_OFF 65536
#define WS_CC_OFF  (65536 + 262144)

__global__ void hgc_flags(const int* __restrict__ e0, const int* __restrict__ e1,
                          const int* __restrict__ e2, const int* __restrict__ e3,
                          unsigned char* __restrict__ flags)
{
    const int tid = threadIdx.x;
    const int b = blockIdx.x;
    const int* ei; int e, E, off;
    if (b < 1250)      { ei = e0; e = b * 256 + tid;          E = E0; off = 0; }
    else if (b < 1875) { ei = e1; e = (b - 1250) * 256 + tid; E = E1; off = N0; }
    else if (b < 2000) { ei = e2; e = (b - 1875) * 256 + tid; E = E2; off = N0 + N1; }
    else               { ei = e3; e = (b - 2000) * 256 + tid; E = E3; off = N0 + N1 + N2; }
    int tgt = ei[E + e];           // row 1 of [2,E] edge_index = targets
    flags[off + tgt] = (unsigned char)1;  // benign race: all writers store 1
}

// WcT[l][j][k] = sum_t Wv[l][k][t] * Wo[l][t][j]   (transposed combined weight)
__global__ void hgc_make_wct(const float* __restrict__ Wv, const float* __restrict__ Wo,
                             float* __restrict__ WcT)
{
    const int b = blockIdx.x;          // 512 blocks: (l, j)
    const int l = b >> 7, j = b & 127;
    const float* wv = Wv + (size_t)l * 128 * 256;
    const float* wo = Wo + (size_t)l * 256 * 128 + j;   // column j, stride 128 (uniform addr)
    const int t = threadIdx.x;         // 64 threads; each does k = t and t+64
#pragma unroll
    for (int kk = 0; kk < 2; ++kk) {
        const int k = t + kk * 64;
        const float4* row4 = (const float4*)(wv + (size_t)k * 256);
        float a0 = 0.f, a1 = 0.f, a2 = 0.f, a3 = 0.f;
        for (int tt = 0; tt < 64; ++tt) {
            float4 r = row4[tt];
            a0 += r.x * wo[(tt * 4 + 0) * 128];
            a1 += r.y * wo[(tt * 4 + 1) * 128];
            a2 += r.z * wo[(tt * 4 + 2) * 128];
            a3 += r.w * wo[(tt * 4 + 3) * 128];
        }
        WcT[(size_t)(l * 128 + j) * 128 + k] = (a0 + a1) + (a2 + a3);
    }
}

// cc[l][j] = sum_t bv[l][t] * Wo[l][t][j] + bo[l][j]
__global__ void hgc_make_cc(const float* __restrict__ bv, const float* __restrict__ Wo,
                            const float* __restrict__ bo, float* __restrict__ cc)
{
    const int l = blockIdx.x;          // 4 blocks x 128 threads
    const int j = threadIdx.x;
    float a = 0.f;
    for (int t = 0; t < 256; ++t)
        a += bv[l * 256 + t] * Wo[((size_t)l * 256 + t) * 128 + j];
    cc[l * 128 + j] = a + bo[l * 128 + j];
}

// Main fused kernel: 2 lanes per node (j-halves), matvec vs WcT, residual + LN.
// block = 128 threads = 64 nodes; out written coalesced via LDS transpose.
__global__ __launch_bounds__(128, 2)
void hgc_main(const float* __restrict__ n0, const float* __restrict__ n1,
              const float* __restrict__ n2, const float* __restrict__ n3,
              const unsigned char* __restrict__ flags,
              const float* __restrict__ WcT, const float* __restrict__ cc,
              const float* __restrict__ bo, const float* __restrict__ gamma,
              const float* __restrict__ beta, float* __restrict__ out)
{
    __shared__ float s_xn[64 * 129];   // [jj][thread], stride 129 kills phase-B conflicts
    __shared__ float s_mean[64];
    __shared__ float s_rstd[64];

    const int tid = threadIdx.x;
    const int t = blockIdx.x * 128 + tid;
    const int p = t >> 1;              // global node id (out rows are contiguous across levels)
    const int half = t & 1;            // which 64-column half this lane computes
    const int pc = (p < NTOT) ? p : 0; // clamp tail lanes to a valid row

    int l, n; const float* nd;
    if (pc < N0)                { l = 0; n = pc;                  nd = n0; }
    else if (pc < N0 + N1)      { l = 1; n = pc - N0;             nd = n1; }
    else if (pc < N0 + N1 + N2) { l = 2; n = pc - (N0 + N1);      nd = n2; }
    else                        { l = 3; n = pc - (N0 + N1 + N2); nd = n3; }

    // whole node row in registers (128 VGPRs)
    const float4* nrow = (const float4*)(nd + (size_t)n * 128);
    float4 xr[32];
#pragma unroll
    for (int q = 0; q < 32; ++q) xr[q] = nrow[q];

    const int fl = flags[pc];
    const int jbase = half << 6;
    const int lj = (l << 7) + jbase;
    const float* wbase = WcT + ((size_t)lj << 7);

    float sum = 0.f, sq = 0.f;
    for (int jj = 0; jj < 64; ++jj) {
        const float4* wr = (const float4*)(wbase + (jj << 7));
        float a0 = 0.f, a1 = 0.f, a2 = 0.f, a3 = 0.f;
#pragma unroll
        for (int q = 0; q < 32; ++q) {
            float4 w = wr[q];
            a0 += xr[q].x * w.x;
            a1 += xr[q].y * w.y;
            a2 += xr[q].z * w.z;
            a3 += xr[q].w * w.w;
        }
        float dot = (a0 + a1) + (a2 + a3);
        float xj  = nd[(size_t)n * 128 + jbase + jj];        // L1-hot reload (avoids dyn reg idx)
        float yv  = fl ? (dot + cc[lj + jj]) : bo[lj + jj];  // no-incoming-edge nodes: agg=0
        float v   = xj + yv;
        s_xn[jj * 129 + tid] = v;
        sum += v; sq += v * v;
    }
    // combine the two halves of each node (lanes 2i, 2i+1)
    sum += __shfl_xor(sum, 1);
    sq  += __shfl_xor(sq, 1);
    float mean = sum * (1.f / 128.f);
    float var  = sq * (1.f / 128.f) - mean * mean;
    float rstd = rsqrtf(var + 1e-5f);
    if (!half) { s_mean[tid >> 1] = mean; s_rstd[tid >> 1] = rstd; }
    __syncthreads();

    // phase B: coalesced stores — thread tid = column, loop over the block's 64 nodes
    float g0 = gamma[tid], g1 = gamma[128 + tid], g2 = gamma[256 + tid], g3 = gamma[384 + tid];
    float b0 = beta[tid],  b1 = beta[128 + tid],  b2 = beta[256 + tid],  b3 = beta[384 + tid];
    const int p0 = blockIdx.x * 64;
    const int jj2 = tid & 63, h2 = tid >> 6;
    for (int q = 0; q < 64; ++q) {
        int pq = p0 + q;
        if (pq >= NTOT) break;                       // uniform tail exit
        int lq = (pq < N0) ? 0 : (pq < N0 + N1) ? 1 : (pq < N0 + N1 + N2) ? 2 : 3;
        float g = (lq == 0) ? g0 : (lq == 1) ? g1 : (lq == 2) ? g2 : g3;
        float b = (lq == 0) ? b0 : (lq == 1) ? b1 : (lq == 2) ? b2 : b3;
        float v = s_xn[jj2 * 129 + 2 * q + h2];
        out[(size_t)pq * 128 + tid] = g * (v - s_mean[q]) * s_rstd[q] + b;
    }
}

extern "C" void kernel_launch(void* const* d_in, const int* in_sizes, int n_in,
                              void* d_out, int out_size, void* d_ws, size_t ws_size,
                              hipStream_t stream)
{
    const float* n0 = (const float*)d_in[0];
    const int*   e0 = (const int*)d_in[2];
    const float* n1 = (const float*)d_in[3];
    const int*   e1 = (const int*)d_in[5];
    const float* n2 = (const float*)d_in[6];
    const int*   e2 = (const int*)d_in[8];
    const float* n3 = (const float*)d_in[9];
    const int*   e3 = (const int*)d_in[11];
    // 12:Wq 13:bq 14:Wk 15:bk 16:Wv 17:bv 18:We 19:be 20:Wo 21:bo 22:gamma 23:beta
    const float* Wv    = (const float*)d_in[16];
    const float* bv    = (const float*)d_in[17];
    const float* Wo    = (const float*)d_in[20];
    const float* bo    = (const float*)d_in[21];
    const float* gamma = (const float*)d_in[22];
    const float* beta  = (const float*)d_in[23];

    unsigned char* flags = (unsigned char*)d_ws;
    float* WcT = (float*)((char*)d_ws + WS_WCT_OFF);
    float* cc  = (float*)((char*)d_ws + WS_CC_OFF);

    hipMemsetAsync(flags, 0, NTOT, stream);
    hgc_flags<<<2025, 256, 0, stream>>>(e0, e1, e2, e3, flags);
    hgc_make_wct<<<512, 64, 0, stream>>>(Wv, Wo, WcT);
    hgc_make_cc<<<4, 128, 0, stream>>>(bv, Wo, bo, cc);

    // 52400 nodes * 2 lanes = 104800 threads; 819 blocks of 128 covers it
    hgc_main<<<819, 128, 0, stream>>>(n0, n1, n2, n3, flags, WcT, cc,
                                      bo, gamma, beta, (float*)d_out);
}

// Round 3
// 228.400 us; speedup vs baseline: 2.0497x; 2.0497x over previous
//
#include <hip/hip_runtime.h>

// HierarchicalGraphConv — v3 (MFMA, fixed W-staging indexing).
// Identity: softmax weights sum to 1 per (target,head) since agg gathers v[tgt],
// so level = LN(x + (has_in_edge ? x@(Wv@Wo) + (bv@Wo+bo) : bo)).
// Main kernel: bf16 MFMA GEMM (16x16x32), X fp32->bf16 staged in LDS, fused
// residual+LayerNorm epilogue via LDS Y roundtrip. fp32 x re-read keeps the
// residual exact; only the matmul term is bf16 (~0.005-0.03 abs err, thr 0.102).

#define N0 40000
#define N1 10000
#define N2 2000
#define N3 400
#define NTOT 52400
#define E0 320000
#define E1 160000
#define E2 32000
#define E3 6400

// ws layout:
//   flags (u8)   @ 0      : 52400 B
//   WcB (bf16)   @ 65536  : 4*128*128*2 = 131072 B   (WcB[l][j][k] = (Wv@Wo)[k][j])
//   cc  (f32)    @ 196608 : 4*128 floats             (bv@Wo + bo)
#define WS_WCB_OFF 65536
#define WS_CC_OFF  196608

typedef __bf16 bf16x8 __attribute__((ext_vector_type(8)));
typedef __bf16 bf16x4 __attribute__((ext_vector_type(4)));
typedef float  f32x4  __attribute__((ext_vector_type(4)));

// LDS strides. X/W rows: 136 bf16 = 272 B (16-aligned rows; frag b128 reads are
// bank-staggered by row). Y rows: 133 f32.
#define XS 136
#define YS 133

__global__ void hgc_flags(const int* __restrict__ e0, const int* __restrict__ e1,
                          const int* __restrict__ e2, const int* __restrict__ e3,
                          unsigned char* __restrict__ flags)
{
    const int tid = threadIdx.x;
    const int b = blockIdx.x;
    const int* ei; int e, E, off;
    if (b < 1250)      { ei = e0; e = b * 256 + tid;          E = E0; off = 0; }
    else if (b < 1875) { ei = e1; e = (b - 1250) * 256 + tid; E = E1; off = N0; }
    else if (b < 2000) { ei = e2; e = (b - 1875) * 256 + tid; E = E2; off = N0 + N1; }
    else               { ei = e3; e = (b - 2000) * 256 + tid; E = E3; off = N0 + N1 + N2; }
    int tgt = ei[E + e];                  // row 1 of [2,E] = targets
    flags[off + tgt] = (unsigned char)1;  // benign race
}

// Block (l,k): WcB[l][j][k] = dot(Wv[l][k][:], Wo[l][:][j]) for all j (128 thr).
// Wv row staged in LDS (lane-uniform broadcast); Wo reads coalesced across j.
// Blocks 512..515: cc[l][j] = dot(bv[l], Wo[l][:][j]) + bo[l][j].
__global__ __launch_bounds__(128)
void hgc_wct(const float* __restrict__ Wv, const float* __restrict__ bv,
             const float* __restrict__ Wo, const float* __restrict__ bo,
             __bf16* __restrict__ WcB, float* __restrict__ cc)
{
    __shared__ float sv[256];
    const int b = blockIdx.x, j = threadIdx.x;
    const bool is_cc = (b >= 512);
    const int l = is_cc ? (b - 512) : (b >> 7);
    const int k = is_cc ? 0 : (b & 127);
    const float* src = is_cc ? (bv + l * 256) : (Wv + ((size_t)l * 128 + k) * 256);
    sv[j] = src[j]; sv[j + 128] = src[j + 128];
    __syncthreads();
    const float* wo = Wo + (size_t)l * 256 * 128 + j;
    float a0 = 0.f, a1 = 0.f, a2 = 0.f, a3 = 0.f;
#pragma unroll 4
    for (int t = 0; t < 256; t += 4) {
        a0 += sv[t + 0] * wo[(t + 0) * 128];
        a1 += sv[t + 1] * wo[(t + 1) * 128];
        a2 += sv[t + 2] * wo[(t + 2) * 128];
        a3 += sv[t + 3] * wo[(t + 3) * 128];
    }
    float r = (a0 + a1) + (a2 + a3);
    if (is_cc) cc[l * 128 + j] = r + bo[l * 128 + j];
    else       WcB[((size_t)l * 128 + j) * 128 + k] = (__bf16)r;
}

// Main: block = 64 nodes x 128 cols, 256 threads (4 waves), wave tile 16x128.
// K-loop: 4 steps of K=32, 8 col-tiles -> 8 mfma_f32_16x16x32_bf16 per step.
__global__ __launch_bounds__(256, 3)
void hgc_main(const float* __restrict__ n0, const float* __restrict__ n1,
              const float* __restrict__ n2, const float* __restrict__ n3,
              const unsigned char* __restrict__ flags,
              const __bf16* __restrict__ WcB, const float* __restrict__ cc,
              const float* __restrict__ bo, const float* __restrict__ gamma,
              const float* __restrict__ beta, float* __restrict__ out)
{
    // union: stage phase = sX(64x136 bf16, 17408 B) + sW(128x136 bf16, 34816 B);
    // epilogue aliases it as sY(64x133 f32, 34048 B). 52224 B + 512 B stats.
    __shared__ __align__(16) char smem[17408 + 34816];
    __shared__ float s_mean[64];
    __shared__ float s_rstd[64];
    __bf16* sX = (__bf16*)smem;
    __bf16* sW = (__bf16*)(smem + 17408);
    float*  sY = (float*)smem;

    const int tid = threadIdx.x;
    const int b = blockIdx.x;
    int l, lb, Nl, goff; const float* nd;
    if (b < 625)      { l = 0; lb = b;       Nl = N0; goff = 0;     nd = n0; }
    else if (b < 782) { l = 1; lb = b - 625; Nl = N1; goff = 40000; nd = n1; }
    else if (b < 814) { l = 2; lb = b - 782; Nl = N2; goff = 50000; nd = n2; }
    else              { l = 3; lb = b - 814; Nl = N3; goff = 52000; nd = n3; }
    const int rbase = lb * 64;

    // ---- stage X (fp32 -> bf16) and W (bf16 copy) into LDS ----
#pragma unroll
    for (int i = 0; i < 8; ++i) {
        int f = tid + 256 * i;                 // float4 index over 64x32 tile
        int r = f >> 5, c4 = f & 31;
        int rr = rbase + r; if (rr >= Nl) rr = Nl - 1;   // clamp tail rows
        float4 v = ((const float4*)(nd + (size_t)rr * 128))[c4];
        bf16x4 p = { (__bf16)v.x, (__bf16)v.y, (__bf16)v.z, (__bf16)v.w };
        *(bf16x4*)(sX + r * XS + c4 * 4) = p;
    }
    const __bf16* wsl = WcB + (size_t)l * 16384;
#pragma unroll
    for (int i = 0; i < 8; ++i) {
        int g = tid + 256 * i;                 // 16B-chunk index: 128 rows x 16 chunks
        int r = g >> 4, o = g & 15;            // FIXED: 16 chunks of 8 bf16 per 128-col row
        *(bf16x8*)(sW + r * XS + o * 8) = *(const bf16x8*)(wsl + r * 128 + o * 8);
    }
    __syncthreads();

    // ---- MFMA K-loop ----
    const int m = tid & 15;          // lane&15 (tid mult-of-64 aligned to waves)
    const int q = (tid >> 4) & 3;    // quad = lane>>4
    const int w = tid >> 6;          // wave id: rows w*16..w*16+15
    const __bf16* ax = sX + (w * 16 + m) * XS + q * 8;
    const __bf16* bx = sW + m * XS + q * 8;

    f32x4 acc[8] = {};
#pragma unroll
    for (int ks = 0; ks < 4; ++ks) {
        bf16x8 a = *(const bf16x8*)(ax + ks * 32);
#pragma unroll
        for (int nt = 0; nt < 8; ++nt) {
            bf16x8 bfr = *(const bf16x8*)(bx + nt * 16 * XS + ks * 32);
            acc[nt] = __builtin_amdgcn_mfma_f32_16x16x32_bf16(a, bfr, acc[nt], 0, 0, 0);
        }
    }
    __syncthreads();   // stage buffers dead; smem becomes sY

    // ---- scatter accumulators to sY: D[row=q*4+reg][col=lane&15] per tile ----
    {
        float* yb = sY + (w * 16 + q * 4) * YS + m;
#pragma unroll
        for (int nt = 0; nt < 8; ++nt)
#pragma unroll
            for (int rg = 0; rg < 4; ++rg)
                yb[rg * YS + nt * 16] = acc[nt][rg];
    }
    __syncthreads();

    // ---- phase A: v = x + (fl ? y+cc : bo); row stats (4 threads/row) ----
    {
        const int r = tid >> 2, qt = tid & 3;
        int rr = rbase + r; int rc = (rr < Nl) ? rr : (Nl - 1);
        const float4* xrow = (const float4*)(nd + (size_t)rc * 128 + qt * 32);
        const int fl = flags[goff + rc];
        float* yr = sY + r * YS + qt * 32;
        const float* ccl = cc + l * 128 + qt * 32;
        const float* bol = bo + l * 128 + qt * 32;
        float sum = 0.f, sq = 0.f;
#pragma unroll
        for (int i = 0; i < 8; ++i) {
            float4 xv = xrow[i];
#pragma unroll
            for (int u = 0; u < 4; ++u) {
                int jj = i * 4 + u;
                float xc = (u == 0) ? xv.x : (u == 1) ? xv.y : (u == 2) ? xv.z : xv.w;
                float y = yr[jj];
                float t = fl ? (y + ccl[jj]) : bol[jj];
                float vv = xc + t;
                yr[jj] = vv;
                sum += vv; sq += vv * vv;
            }
        }
        sum += __shfl_xor(sum, 1); sq += __shfl_xor(sq, 1);
        sum += __shfl_xor(sum, 2); sq += __shfl_xor(sq, 2);
        if (qt == 0) {
            float mean = sum * (1.f / 128.f);
            float var  = sq * (1.f / 128.f) - mean * mean;
            s_mean[r] = mean;
            s_rstd[r] = rsqrtf(var + 1e-5f);
        }
    }
    __syncthreads();

    // ---- phase B: coalesced LN store (thread = column, 2 row-phases) ----
    {
        const int c = tid & 127, h = tid >> 7;
        const float g  = gamma[l * 128 + c];
        const float bt = beta[l * 128 + c];
#pragma unroll 4
        for (int i = 0; i < 32; ++i) {
            int qrow = h + 2 * i;
            int rr = rbase + qrow;
            if (rr >= Nl) break;
            float v = sY[qrow * YS + c];
            out[((size_t)(goff + rr)) * 128 + c] = g * (v - s_mean[qrow]) * s_rstd[qrow] + bt;
        }
    }
}

extern "C" void kernel_launch(void* const* d_in, const int* in_sizes, int n_in,
                              void* d_out, int out_size, void* d_ws, size_t ws_size,
                              hipStream_t stream)
{
    const float* n0 = (const float*)d_in[0];
    const int*   e0 = (const int*)d_in[2];
    const float* n1 = (const float*)d_in[3];
    const int*   e1 = (const int*)d_in[5];
    const float* n2 = (const float*)d_in[6];
    const int*   e2 = (const int*)d_in[8];
    const float* n3 = (const float*)d_in[9];
    const int*   e3 = (const int*)d_in[11];
    // 12:Wq 13:bq 14:Wk 15:bk 16:Wv 17:bv 18:We 19:be 20:Wo 21:bo 22:gamma 23:beta
    const float* Wv    = (const float*)d_in[16];
    const float* bv    = (const float*)d_in[17];
    const float* Wo    = (const float*)d_in[20];
    const float* bo    = (const float*)d_in[21];
    const float* gamma = (const float*)d_in[22];
    const float* beta  = (const float*)d_in[23];

    unsigned char* flags = (unsigned char*)d_ws;
    __bf16* WcB = (__bf16*)((char*)d_ws + WS_WCB_OFF);
    float*  cc  = (float*)((char*)d_ws + WS_CC_OFF);

    hipMemsetAsync(flags, 0, NTOT, stream);
    hgc_flags<<<2025, 256, 0, stream>>>(e0, e1, e2, e3, flags);
    hgc_wct<<<516, 128, 0, stream>>>(Wv, bv, Wo, bo, WcB, cc);

    // blocks: L0 625 (exact), L1 157, L2 32, L3 7 -> 821
    hgc_main<<<821, 256, 0, stream>>>(n0, n1, n2, n3, flags, WcB, cc,
                                      bo, gamma, beta, (float*)d_out);
}

// Round 4
// 223.174 us; speedup vs baseline: 2.0977x; 1.0234x over previous
//
#include <hip/hip_runtime.h>

// HierarchicalGraphConv — v4.
// Identity: softmax weights sum to 1 per (target,head) since agg gathers v[tgt],
// so level = LN(x + (has_in_edge ? x@(Wv@Wo) + (bv@Wo+bo) : bo)).
// v4: B-frags straight from global (L2-hot, no sW stage), X staged fp32 in LDS
// (exact residual, no global re-read), in-register row stats via shfl butterfly,
// 2 barriers, 3 launches total (memset + prep + main).

#define N0 40000
#define N1 10000
#define N2 2000
#define N3 400
#define NTOT 52400
#define E0 320000
#define E1 160000
#define E2 32000
#define E3 6400

// ws layout:
//   flags (u8)   @ 0      : 52400 B
//   WcB (bf16)   @ 65536  : 4*128*128*2 = 131072 B   (WcB[l][n][k] = (Wv@Wo)[k][n])
//   cc  (f32)    @ 196608 : 4*128 floats             (bv@Wo + bo)
#define WS_WCB_OFF 65536
#define WS_CC_OFF  196608

typedef __bf16 bf16x8 __attribute__((ext_vector_type(8)));
typedef float  f32x4  __attribute__((ext_vector_type(4)));

#define XS 132   // fp32 LDS row stride (mod 32 = 4): all access phases conflict-free

// One prep kernel: blocks [0,509) flags scatter (int4, 4 edges/thr),
// [509,765) WcT columns (2 k per block), [765,767) cc.
__global__ __launch_bounds__(256)
void hgc_prep(const int* __restrict__ e0, const int* __restrict__ e1,
              const int* __restrict__ e2, const int* __restrict__ e3,
              const float* __restrict__ Wv, const float* __restrict__ bv,
              const float* __restrict__ Wo, const float* __restrict__ bo,
              unsigned char* __restrict__ flags, __bf16* __restrict__ WcB,
              float* __restrict__ cc)
{
    __shared__ float sv[512];
    const int b = blockIdx.x, tid = threadIdx.x;
    if (b < 509) {
        const int* ei; int E, off, lb;
        if (b < 313)      { ei = e0; E = E0; off = 0;            lb = b; }
        else if (b < 470) { ei = e1; E = E1; off = N0;           lb = b - 313; }
        else if (b < 502) { ei = e2; E = E2; off = N0 + N1;      lb = b - 470; }
        else              { ei = e3; E = E3; off = N0 + N1 + N2; lb = b - 502; }
        int e = lb * 1024 + tid * 4;
        if (e < E) {
            int4 t4 = *(const int4*)(ei + E + e);   // row 1 of [2,E] = targets
            flags[off + t4.x] = 1; flags[off + t4.y] = 1;
            flags[off + t4.z] = 1; flags[off + t4.w] = 1;
        }
        return;
    }
    if (b < 765) {
        // WcB[l][j][k] = dot(Wv[l][k][:], Wo[l][:][j]); this block: k = 2kp, 2kp+1
        const int w = b - 509, l = w >> 6, kp = w & 63;
        const float* src = Wv + ((size_t)l * 128 + kp * 2) * 256;
        sv[tid] = src[tid]; sv[tid + 256] = src[tid + 256];
        __syncthreads();
        const int half = tid >> 7, j = tid & 127;
        const float* svh = sv + half * 256;
        const float* wo = Wo + (size_t)l * 256 * 128 + j;
        float a0 = 0.f, a1 = 0.f, a2 = 0.f, a3 = 0.f;
#pragma unroll 4
        for (int t = 0; t < 256; t += 4) {
            a0 += svh[t + 0] * wo[(t + 0) * 128];
            a1 += svh[t + 1] * wo[(t + 1) * 128];
            a2 += svh[t + 2] * wo[(t + 2) * 128];
            a3 += svh[t + 3] * wo[(t + 3) * 128];
        }
        WcB[((size_t)l * 128 + j) * 128 + kp * 2 + half] = (__bf16)((a0 + a1) + (a2 + a3));
        return;
    }
    {   // cc[l][j] = dot(bv[l], Wo[l][:][j]) + bo[l][j]
        const int idx = (b - 765) * 256 + tid;
        const int l = idx >> 7, j = idx & 127;
        const float* wo = Wo + (size_t)l * 256 * 128 + j;
        const float* bvl = bv + l * 256;
        float a0 = 0.f, a1 = 0.f, a2 = 0.f, a3 = 0.f;
#pragma unroll 4
        for (int t = 0; t < 256; t += 4) {
            a0 += bvl[t + 0] * wo[(t + 0) * 128];
            a1 += bvl[t + 1] * wo[(t + 1) * 128];
            a2 += bvl[t + 2] * wo[(t + 2) * 128];
            a3 += bvl[t + 3] * wo[(t + 3) * 128];
        }
        cc[idx] = (a0 + a1) + (a2 + a3) + bo[idx];
    }
}

// Main: block = 64 nodes x 128 cols, 256 threads (4 waves), wave tile 16x128.
// A from LDS fp32 (cvt in-reg), B from global (L2-hot), fused residual+LN.
__global__ __launch_bounds__(256, 4)
void hgc_main(const float* __restrict__ n0, const float* __restrict__ n1,
              const float* __restrict__ n2, const float* __restrict__ n3,
              const unsigned char* __restrict__ flags,
              const __bf16* __restrict__ WcB, const float* __restrict__ cc,
              const float* __restrict__ bo, const float* __restrict__ gamma,
              const float* __restrict__ beta, float* __restrict__ out)
{
    __shared__ float sX[64 * XS];      // 33792 B; holds x, then v in-place
    __shared__ float s_mean[64];
    __shared__ float s_rstd[64];

    const int tid = threadIdx.x;
    const int b = blockIdx.x;
    int l, lb, Nl, goff; const float* nd;
    if (b < 625)      { l = 0; lb = b;       Nl = N0; goff = 0;     nd = n0; }
    else if (b < 782) { l = 1; lb = b - 625; Nl = N1; goff = 40000; nd = n1; }
    else if (b < 814) { l = 2; lb = b - 782; Nl = N2; goff = 50000; nd = n2; }
    else              { l = 3; lb = b - 814; Nl = N3; goff = 52000; nd = n3; }
    const int rbase = lb * 64;

    // ---- stage X fp32 into LDS (coalesced float4; clamp tail rows) ----
#pragma unroll
    for (int i = 0; i < 8; ++i) {
        int f = tid + 256 * i;                 // float4 index over 64x32 tile
        int r = f >> 5, c4 = f & 31;
        int rr = rbase + r; if (rr >= Nl) rr = Nl - 1;
        float4 v = ((const float4*)(nd + (size_t)rr * 128))[c4];
        *(float4*)(sX + r * XS + c4 * 4) = v;  // row stride 528 B (16-aligned)
    }
    __syncthreads();

    // ---- MFMA K-loop: A = cvt(sX), B = global WcB (L2-hot) ----
    const int m = tid & 15;
    const int q = (tid >> 4) & 3;
    const int w = tid >> 6;
    const float* axf = sX + (w * 16 + m) * XS + q * 8;
    const __bf16* wl = WcB + (size_t)l * 16384 + (size_t)m * 128 + q * 8;

    f32x4 acc[8] = {};
#pragma unroll
    for (int ks = 0; ks < 4; ++ks) {
        float4 xa = *(const float4*)(axf + ks * 32);
        float4 xb = *(const float4*)(axf + ks * 32 + 4);
        bf16x8 a = { (__bf16)xa.x, (__bf16)xa.y, (__bf16)xa.z, (__bf16)xa.w,
                     (__bf16)xb.x, (__bf16)xb.y, (__bf16)xb.z, (__bf16)xb.w };
#pragma unroll
        for (int nt = 0; nt < 8; ++nt) {
            bf16x8 bfr = *(const bf16x8*)(wl + nt * 2048 + ks * 32);
            acc[nt] = __builtin_amdgcn_mfma_f32_16x16x32_bf16(a, bfr, acc[nt], 0, 0, 0);
        }
    }

    // ---- fused epilogue, part 1: v = x + (fl ? y+cc : bo) at C-layout slots.
    // Lane owns rows r0..r0+3 (r0 = w*16+q*4), cols m+16nt — disjoint per lane,
    // so in-place sX update is hazard-free; row stats via shfl over the m-group.
    {
        const int r0 = w * 16 + q * 4;
        int fl[4];
#pragma unroll
        for (int rg = 0; rg < 4; ++rg) {
            int rr = rbase + r0 + rg; if (rr >= Nl) rr = Nl - 1;
            fl[rg] = flags[goff + rr];
        }
        float cc8[8], bo8[8];
#pragma unroll
        for (int nt = 0; nt < 8; ++nt) {
            cc8[nt] = cc[l * 128 + m + 16 * nt];
            bo8[nt] = bo[l * 128 + m + 16 * nt];
        }
        float sum[4] = {}, sq[4] = {};
#pragma unroll
        for (int rg = 0; rg < 4; ++rg) {
            float* xr = sX + (r0 + rg) * XS + m;
#pragma unroll
            for (int nt = 0; nt < 8; ++nt) {
                float x = xr[16 * nt];
                float t = fl[rg] ? (acc[nt][rg] + cc8[nt]) : bo8[nt];
                float v = x + t;
                xr[16 * nt] = v;
                sum[rg] += v; sq[rg] += v * v;
            }
        }
#pragma unroll
        for (int s = 1; s < 16; s <<= 1) {
#pragma unroll
            for (int rg = 0; rg < 4; ++rg) {
                sum[rg] += __shfl_xor(sum[rg], s);
                sq[rg]  += __shfl_xor(sq[rg], s);
            }
        }
        if (m == 0) {
#pragma unroll
            for (int rg = 0; rg < 4; ++rg) {
                float mean = sum[rg] * (1.f / 128.f);
                float var  = sq[rg] * (1.f / 128.f) - mean * mean;
                s_mean[r0 + rg] = mean;
                s_rstd[r0 + rg] = rsqrtf(var + 1e-5f);
            }
        }
    }
    __syncthreads();

    // ---- part 2: coalesced LN stores (float2 per thread, 16 rows each) ----
    {
        const int c = (tid & 63) * 2, h = tid >> 6;
        const float g0 = gamma[l * 128 + c],     g1 = gamma[l * 128 + c + 1];
        const float t0 = beta[l * 128 + c],      t1 = beta[l * 128 + c + 1];
#pragma unroll 4
        for (int i = 0; i < 16; ++i) {
            int qrow = h + 4 * i;
            int rr = rbase + qrow;
            if (rr >= Nl) continue;
            float2 v = *(const float2*)(sX + qrow * XS + c);
            float mu = s_mean[qrow], rs = s_rstd[qrow];
            float2 o;
            o.x = g0 * (v.x - mu) * rs + t0;
            o.y = g1 * (v.y - mu) * rs + t1;
            *(float2*)(out + (size_t)(goff + rr) * 128 + c) = o;
        }
    }
}

extern "C" void kernel_launch(void* const* d_in, const int* in_sizes, int n_in,
                              void* d_out, int out_size, void* d_ws, size_t ws_size,
                              hipStream_t stream)
{
    const float* n0 = (const float*)d_in[0];
    const int*   e0 = (const int*)d_in[2];
    const float* n1 = (const float*)d_in[3];
    const int*   e1 = (const int*)d_in[5];
    const float* n2 = (const float*)d_in[6];
    const int*   e2 = (const int*)d_in[8];
    const float* n3 = (const float*)d_in[9];
    const int*   e3 = (const int*)d_in[11];
    // 12:Wq 13:bq 14:Wk 15:bk 16:Wv 17:bv 18:We 19:be 20:Wo 21:bo 22:gamma 23:beta
    const float* Wv    = (const float*)d_in[16];
    const float* bv    = (const float*)d_in[17];
    const float* Wo    = (const float*)d_in[20];
    const float* bo    = (const float*)d_in[21];
    const float* gamma = (const float*)d_in[22];
    const float* beta  = (const float*)d_in[23];

    unsigned char* flags = (unsigned char*)d_ws;
    __bf16* WcB = (__bf16*)((char*)d_ws + WS_WCB_OFF);
    float*  cc  = (float*)((char*)d_ws + WS_CC_OFF);

    hipMemsetAsync(flags, 0, NTOT, stream);
    hgc_prep<<<767, 256, 0, stream>>>(e0, e1, e2, e3, Wv, bv, Wo, bo,
                                      flags, WcB, cc);
    // blocks: L0 625, L1 157, L2 32, L3 7 -> 821
    hgc_main<<<821, 256, 0, stream>>>(n0, n1, n2, n3, flags, WcB, cc,
                                      bo, gamma, beta, (float*)d_out);
}